// Round 7
// baseline (421.748 us; speedup 1.0000x reference)
//
#include <hip/hip_runtime.h>
#include <hip/hip_bf16.h>
#include <type_traits>

using bf16 = __hip_bfloat16;
typedef __bf16 bf16x8 __attribute__((ext_vector_type(8)));
typedef float f32x4 __attribute__((ext_vector_type(4)));

static constexpr int TOKENS = 4 * 128 * 128;  // 65536
#define SCALE_F 0.11180339887498949f          // 1/sqrt(64+16)
#define EPS_F 1e-6f

__device__ __forceinline__ float u2f(unsigned short u) {
  union { unsigned int i; float f; } c; c.i = (unsigned int)u << 16; return c.f;
}
__device__ __forceinline__ unsigned short f2u(float f) {
  bf16 h = __float2bfloat16(f); return *reinterpret_cast<unsigned short*>(&h);
}
__device__ __forceinline__ float b2f(bf16 v) { return __bfloat162float(v); }
// load 8 f32, round to 8 bf16 packed in an int4
__device__ __forceinline__ int4 cvt8(const float* p) {
  float4 a = ((const float4*)p)[0], b = ((const float4*)p)[1];
  union { int4 i4; unsigned short s[8]; } u;
  u.s[0] = f2u(a.x); u.s[1] = f2u(a.y); u.s[2] = f2u(a.z); u.s[3] = f2u(a.w);
  u.s[4] = f2u(b.x); u.s[5] = f2u(b.y); u.s[6] = f2u(b.z); u.s[7] = f2u(b.w);
  return u.i4;
}
// async global->LDS, 16 bytes per lane (m97 mechanism)
__device__ __forceinline__ void gload16(const bf16* g, bf16* l) {
  __builtin_amdgcn_global_load_lds(
      (const __attribute__((address_space(1))) unsigned int*)g,
      (__attribute__((address_space(3))) unsigned int*)l, 16, 0, 0);
}

// ---------------- f32 -> bf16 bulk convert ----------------
__global__ void convert_k(const float* __restrict__ in, bf16* __restrict__ out,
                          long n) {
  long i = ((long)blockIdx.x * 256 + threadIdx.x) * 8;
  long stride = (long)gridDim.x * 256 * 8;
  for (; i < n; i += stride) *(int4*)(out + i) = cvt8(in + i);
}

// ---------------- weight transpose + f32->bf16: out[N][K] = in[K][N] ------
__global__ void transpose_k(const float* __restrict__ in, bf16* __restrict__ out,
                            int K, int N) {
  int i = blockIdx.x * 256 + threadIdx.x;
  if (i >= K * N) return;
  int k = i / N, n = i - k * N;
  out[(size_t)n * K + k] = __float2bfloat16(in[i]);
}

__global__ void biascat_k(const float* __restrict__ a, const float* __restrict__ b,
                          float* __restrict__ o) {
  int i = blockIdx.x * 256 + threadIdx.x;
  if (i < 1536) o[i] = i < 1024 ? a[i] : b[i - 1024];
}

// ---------------- GEMM: C[M,N] = A @ Wt^T + bias --------------------------
// BM=BN=128, BK=32, 4 waves 2x2. Depth-2 pipeline, 3 LDS buffers, counted
// vmcnt (T4: never drain to 0 in-loop), ONE raw s_barrier per K-step.
// Iter t: vmcnt(4) [tile t landed, t+1 in flight] -> barrier -> stage t+2
// into buf[(t-1)%3] (all waves finished its reads at this barrier) ->
// ds_read+MFMA tile t. Transposed-D epilogue; T2 read swizzle both-sides.
template <typename TC, int SSNX>
__global__ __launch_bounds__(256) void gemm128_k(
    const bf16* __restrict__ A, const bf16* __restrict__ Wt,
    const float* __restrict__ bias, TC* __restrict__ C,
    float* __restrict__ ssq, int M, int N, int K) {
  __shared__ __align__(16) bf16 sA[3][4096];
  __shared__ __align__(16) bf16 sB[3][4096];
  const int t = threadIdx.x, lane = t & 63, wave = t >> 6;
  const int wr = wave >> 1, wc = wave & 1;
  // T1: bijective chunked XCD swizzle (nwg % 8 == 0 for all our grids)
  const int nwg = gridDim.x * gridDim.y;
  int id = blockIdx.y * gridDim.x + blockIdx.x;
  if ((nwg & 7) == 0) id = (id & 7) * (nwg >> 3) + (id >> 3);
  const int bx = id % gridDim.x, by = id / gridDim.x;
  const int bm = by * 128, bn = bx * 128;
  const int l15 = lane & 15, kg = lane >> 4;
  f32x4 acc[4][4] = {};  // [i: feat frag][j: token frag]

  const int srow = t >> 2;                            // staging row 0..63
  const int ske = ((t & 3) ^ ((srow >> 1) & 3)) * 8;  // pre-swizzled chunk
  const bf16* pA0 = A + (size_t)(bm + srow) * K + ske;
  const bf16* pA1 = A + (size_t)(bm + 64 + srow) * K + ske;
  const bf16* pB0 = Wt + (size_t)(bn + srow) * K + ske;
  const bf16* pB1 = Wt + (size_t)(bn + 64 + srow) * K + ske;
  const int wo = wave * 512;
  const int nt = K >> 5;

  // prologue: stage tiles 0 and 1
  gload16(pA0, &sA[0][wo]);
  gload16(pA1, &sA[0][2048 + wo]);
  gload16(pB0, &sB[0][wo]);
  gload16(pB1, &sB[0][2048 + wo]);
  pA0 += 32; pA1 += 32; pB0 += 32; pB1 += 32;
  gload16(pA0, &sA[1][wo]);
  gload16(pA1, &sA[1][2048 + wo]);
  gload16(pB0, &sB[1][wo]);
  gload16(pB1, &sB[1][2048 + wo]);

  int cur = 0, prv = 2;
  for (int tt = 0; tt < nt; ++tt) {
    if (tt + 1 < nt) {
      asm volatile("s_waitcnt vmcnt(4)" ::: "memory");
    } else {
      asm volatile("s_waitcnt vmcnt(0)" ::: "memory");
    }
    __builtin_amdgcn_s_barrier();
    __builtin_amdgcn_sched_barrier(0);
    if (tt + 2 < nt) {  // stage tile t+2 into buffer read at iter t-1
      pA0 += 32; pA1 += 32; pB0 += 32; pB1 += 32;
      gload16(pA0, &sA[prv][wo]);
      gload16(pA1, &sA[prv][2048 + wo]);
      gload16(pB0, &sB[prv][wo]);
      gload16(pB1, &sB[prv][2048 + wo]);
    }
    bf16x8 wf[4], xf[4];
#pragma unroll
    for (int i = 0; i < 4; ++i) {
      int frow = wc * 64 + i * 16 + l15;   // weight row (feature)
      int xrow = wr * 64 + i * 16 + l15;   // token row
      wf[i] = *(const bf16x8*)(&sB[cur][frow * 32 + ((kg ^ ((frow >> 1) & 3)) * 8)]);
      xf[i] = *(const bf16x8*)(&sA[cur][xrow * 32 + ((kg ^ ((xrow >> 1) & 3)) * 8)]);
    }
#pragma unroll
    for (int i = 0; i < 4; ++i)
#pragma unroll
      for (int j = 0; j < 4; ++j)
        acc[i][j] = __builtin_amdgcn_mfma_f32_16x16x32_bf16(wf[i], xf[j], acc[i][j], 0, 0, 0);
    prv = cur;
    cur = (cur == 2) ? 0 : cur + 1;
  }

  // epilogue: feat = bn + wc*64 + i*16 + kg*4 + r ; token = bm + wr*64 + j*16 + l15
  float bvi[4][4];
#pragma unroll
  for (int i = 0; i < 4; ++i) {
    float4 b4 = *(const float4*)(bias + bn + wc * 64 + i * 16 + kg * 4);
    bvi[i][0] = b4.x; bvi[i][1] = b4.y; bvi[i][2] = b4.z; bvi[i][3] = b4.w;
  }
#pragma unroll
  for (int j = 0; j < 4; ++j) {
    const int token = bm + wr * 64 + j * 16 + l15;
    float ssum = 0.f;
#pragma unroll
    for (int i = 0; i < 4; ++i) {
      float v0 = acc[i][j][0] + bvi[i][0];
      float v1 = acc[i][j][1] + bvi[i][1];
      float v2 = acc[i][j][2] + bvi[i][2];
      float v3 = acc[i][j][3] + bvi[i][3];
      const size_t off = (size_t)token * N + bn + wc * 64 + i * 16 + kg * 4;
      if constexpr (std::is_same<TC, float>::value) {
        *(float4*)(C + off) = float4{v0, v1, v2, v3};
      } else {
        ushort4 pk{f2u(v0), f2u(v1), f2u(v2), f2u(v3)};
        *(ushort4*)(C + off) = pk;
      }
      if constexpr (SSNX > 0)
        ssum += v0 * v0 + v1 * v1 + v2 * v2 + v3 * v3;
    }
    if constexpr (SSNX > 0) {
      ssum += __shfl_xor(ssum, 16);
      ssum += __shfl_xor(ssum, 32);
      if (bx < SSNX && kg == 0)
        ssq[(size_t)token * (SSNX * 2) + bx * 2 + wc] = ssum;
    }
  }
}

// ---------------- finalize: partial sumsq -> per-token rsqrt scales -------
__global__ void finalize_rs_k(const float* __restrict__ pf,
                              const float* __restrict__ pc,
                              float* __restrict__ rsf, float* __restrict__ rsc) {
  int i = blockIdx.x * 256 + threadIdx.x;
  if (i >= TOKENS) return;
  float s = 0.f;
#pragma unroll
  for (int j = 0; j < 16; ++j) s += pf[(size_t)i * 16 + j];
  rsf[i] = rsqrtf(s * (1.f / 1024.f) + EPS_F);
  float c = 0.f;
#pragma unroll
  for (int j = 0; j < 4; ++j) c += pc[(size_t)i * 4 + j];
  rsc[i] = rsqrtf(c * (1.f / 256.f) + EPS_F);
}

// ---------------- MFMA windowed attention: one block per (window, head) ---
// qkv rows hold RAW q|k|v. Normalization applied here: K-side staged with
// G[d]=g_q[d]*g_k[d] folded in; S fragments scaled by rs_q*rs_k per part.
__global__ __launch_bounds__(256) void attn_mfma_k(
    const bf16* __restrict__ qkv, const bf16* __restrict__ cqk,
    const float* __restrict__ pos, const float* __restrict__ g_fqk,
    const float* __restrict__ g_cqk, const float* __restrict__ rs_f,
    const float* __restrict__ rs_c, bf16* __restrict__ aout) {
  __shared__ __align__(16) bf16 sQ[64][104], sK[64][104];  // 96 used + pad
  __shared__ __align__(16) bf16 sVt[64][72];               // [d][kk]
  __shared__ __align__(16) bf16 sP[64][72];                // [q][kk]
  __shared__ float sPos[15][15];
  __shared__ float sRsF[64], sRsC[64];
  const int t = threadIdx.x, lane = t & 63, wave = t >> 6;
  const int head = blockIdx.x & 7;
  const int wid = blockIdx.x >> 3;
  const int wx = wid & 15, wy = (wid >> 4) & 15, b = wid >> 8;

  for (int i = t; i < 225; i += 256) sPos[i / 15][i % 15] = pos[i];
  if (t < 64) {
    const int y = ((wy << 3) + (t >> 3) + 4) & 127;
    const int x = ((wx << 3) + (t & 7) + 4) & 127;
    const size_t tok = ((size_t)b << 14) | (y << 7) | x;
    sRsF[t] = rs_f[tok];
    sRsC[t] = rs_c[tok];
  }
  {
    const int n = t >> 2, p = t & 3;
    const int y = ((wy << 3) + (n >> 3) + 4) & 127;
    const int x = ((wx << 3) + (n & 7) + 4) & 127;
    const size_t tok = ((size_t)b << 14) | (y << 7) | x;
    const bf16* row = qkv + tok * 1536;
    // Q: raw copy (16 elems)
    const int4* qp = (const int4*)(row + head * 64 + p * 16);
    ((int4*)&sQ[n][p * 16])[0] = qp[0];
    ((int4*)&sQ[n][p * 16])[1] = qp[1];
    // K: multiply by G[d] = g_q[d]*g_k[d]
    {
      const bf16* kpp = row + 512 + head * 64 + p * 16;
      const float* gq = g_fqk + head * 64 + p * 16;
      const float* gk = g_fqk + 512 + head * 64 + p * 16;
      union { int4 v[2]; unsigned short s[16]; } kt;
#pragma unroll
      for (int i = 0; i < 16; ++i)
        kt.s[i] = f2u(b2f(kpp[i]) * gq[i] * gk[i]);
      ((int4*)&sK[n][p * 16])[0] = kt.v[0];
      ((int4*)&sK[n][p * 16])[1] = kt.v[1];
    }
    // V: transposed scatter
    const bf16* vp = row + 1024 + head * 64 + p * 16;
#pragma unroll
    for (int i = 0; i < 16; ++i) sVt[p * 16 + i][n] = vp[i];
    // coords + zero padding
    const bf16* crow = cqk + tok * 256;
    if (p == 0) {  // CQ raw
      const int4* cp = (const int4*)(crow + head * 16);
      ((int4*)&sQ[n][64])[0] = cp[0];
      ((int4*)&sQ[n][64])[1] = cp[1];
    } else if (p == 1) {  // CK * Gc
      const bf16* ckp = crow + 128 + head * 16;
      const float* gcq = g_cqk + head * 16;
      const float* gck = g_cqk + 128 + head * 16;
      union { int4 v[2]; unsigned short s[16]; } ct;
#pragma unroll
      for (int i = 0; i < 16; ++i)
        ct.s[i] = f2u(b2f(ckp[i]) * gcq[i] * gck[i]);
      ((int4*)&sK[n][64])[0] = ct.v[0];
      ((int4*)&sK[n][64])[1] = ct.v[1];
    } else if (p == 2) {
      ((int4*)&sQ[n][80])[0] = int4{0, 0, 0, 0};
      ((int4*)&sQ[n][80])[1] = int4{0, 0, 0, 0};
    } else {
      ((int4*)&sK[n][80])[0] = int4{0, 0, 0, 0};
      ((int4*)&sK[n][80])[1] = int4{0, 0, 0, 0};
    }
  }
  __syncthreads();

  // ---- S: feature part (K=64, 2 MFMAs) + coord part (K=32, 1 MFMA) ----
  const int l15 = lane & 15, kg = lane >> 4;
  bf16x8 qa[3];
#pragma unroll
  for (int ko = 0; ko < 3; ++ko)
    qa[ko] = *(const bf16x8*)&sQ[wave * 16 + l15][ko * 32 + kg * 8];
  f32x4 saccf[4] = {}, saccc[4] = {};
#pragma unroll
  for (int j = 0; j < 4; ++j) {
#pragma unroll
    for (int ko = 0; ko < 2; ++ko) {
      bf16x8 kb = *(const bf16x8*)&sK[j * 16 + l15][ko * 32 + kg * 8];
      saccf[j] = __builtin_amdgcn_mfma_f32_16x16x32_bf16(qa[ko], kb, saccf[j], 0, 0, 0);
    }
    bf16x8 kb2 = *(const bf16x8*)&sK[j * 16 + l15][64 + kg * 8];
    saccc[j] = __builtin_amdgcn_mfma_f32_16x16x32_bf16(qa[2], kb2, saccc[j], 0, 0, 0);
  }

  // ---- softmax in-register: rows wave*16 + kg*4 + r, cols j*16 + l15 ----
  const bool lastx = (wx == 15), lasty = (wy == 15);
  float rqf[4], rqc[4];
#pragma unroll
  for (int r = 0; r < 4; ++r) {
    rqf[r] = sRsF[wave * 16 + kg * 4 + r];
    rqc[r] = sRsC[wave * 16 + kg * 4 + r];
  }
  float sv[4][4], mx[4], sum[4], inv[4];
#pragma unroll
  for (int r = 0; r < 4; ++r) mx[r] = -1e30f;
#pragma unroll
  for (int j = 0; j < 4; ++j) {
    int kcol = j * 16 + l15, kh = kcol >> 3, kw = kcol & 7;
    float rkf = sRsF[kcol], rkc = sRsC[kcol];
#pragma unroll
    for (int r = 0; r < 4; ++r) {
      int q = wave * 16 + kg * 4 + r, qh = q >> 3, qw = q & 7;
      bool msk = (lastx && ((qh >= 4) != (kh >= 4))) ||
                 (lasty && ((qw >= 4) != (kw >= 4)));
      float raw = saccf[j][r] * rqf[r] * rkf + saccc[j][r] * rqc[r] * rkc;
      float val = msk ? -1e30f : raw * SCALE_F + sPos[kh - qh + 7][kw - qw + 7];
      sv[j][r] = val;
      mx[r] = fmaxf(mx[r], val);
    }
  }
#pragma unroll
  for (int m = 1; m < 16; m <<= 1)
#pragma unroll
    for (int r = 0; r < 4; ++r) mx[r] = fmaxf(mx[r], __shfl_xor(mx[r], m));
#pragma unroll
  for (int r = 0; r < 4; ++r) sum[r] = 0.f;
#pragma unroll
  for (int j = 0; j < 4; ++j) {
    int kcol = j * 16 + l15;
#pragma unroll
    for (int r = 0; r < 4; ++r) {
      float e = __expf(sv[j][r] - mx[r]);
      sum[r] += e;
      sP[wave * 16 + kg * 4 + r][kcol] = __float2bfloat16(e);
    }
  }
#pragma unroll
  for (int m = 1; m < 16; m <<= 1)
#pragma unroll
    for (int r = 0; r < 4; ++r) sum[r] += __shfl_xor(sum[r], m);
#pragma unroll
  for (int r = 0; r < 4; ++r) inv[r] = 1.f / sum[r];
  __syncthreads();

  // ---- O = P.V (rows wave*16..), V^T staged; scale by inv at epilogue ----
  bf16x8 pa[2];
#pragma unroll
  for (int ko = 0; ko < 2; ++ko)
    pa[ko] = *(const bf16x8*)&sP[wave * 16 + l15][ko * 32 + kg * 8];
  f32x4 oacc[4] = {};
#pragma unroll
  for (int jf = 0; jf < 4; ++jf)
#pragma unroll
    for (int ko = 0; ko < 2; ++ko) {
      bf16x8 vb = *(const bf16x8*)&sVt[jf * 16 + l15][ko * 32 + kg * 8];
      oacc[jf] = __builtin_amdgcn_mfma_f32_16x16x32_bf16(pa[ko], vb, oacc[jf], 0, 0, 0);
    }
#pragma unroll
  for (int r = 0; r < 4; ++r) {
    int q = wave * 16 + kg * 4 + r;
    const int y = ((wy << 3) + (q >> 3) + 4) & 127;
    const int x = ((wx << 3) + (q & 7) + 4) & 127;
    const size_t tok = ((size_t)b << 14) | (y << 7) | x;
    bf16* dst = aout + tok * 512 + head * 64;
#pragma unroll
    for (int jf = 0; jf < 4; ++jf)
      dst[jf * 16 + l15] = __float2bfloat16(oacc[jf][r] * inv[r]);
  }
}

extern "C" void kernel_launch(void* const* d_in, const int* in_sizes, int n_in,
                              void* d_out, int out_size, void* d_ws, size_t ws_size,
                              hipStream_t stream) {
  const float* features = (const float*)d_in[0];
  const float* coords   = (const float*)d_in[1];
  const float* w_fqk = (const float*)d_in[2];
  const float* b_fqk = (const float*)d_in[3];
  const float* g_fqk = (const float*)d_in[4];
  const float* w_cqk = (const float*)d_in[5];
  const float* b_cqk = (const float*)d_in[6];
  const float* g_cqk = (const float*)d_in[7];
  const float* w_v   = (const float*)d_in[8];
  const float* b_v   = (const float*)d_in[9];
  const float* w_out = (const float*)d_in[10];
  const float* b_out = (const float*)d_in[11];
  const float* pos_emb = (const float*)d_in[12];
  float* out = (float*)d_out;

  const int M = TOKENS;  // 65536
  // workspace layout
  bf16* qkv   = (bf16*)d_ws;                       // M*1536 (raw q|k|v)
  bf16* cqk   = qkv + (size_t)M * 1536;            // M*256 (raw cq|ck)
  bf16* aout  = cqk + (size_t)M * 256;             // M*512
  bf16* wcombT = aout + (size_t)M * 512;           // 1536*512
  bf16* wcqkT  = wcombT + (size_t)1536 * 512;      // 256*128
  bf16* woutT  = wcqkT + 256 * 128;                // 512*512
  float* bias_comb = (float*)(woutT + 512 * 512);  // 1536 f32
  float* ssq_f = bias_comb + 1536;                 // M*16 f32
  float* ssq_c = ssq_f + (size_t)M * 16;           // M*4 f32
  float* rs_f  = ssq_c + (size_t)M * 4;            // M f32
  float* rs_c  = rs_f + M;                         // M f32
  // temp bf16 inputs aliased into d_out (dead until final GEMM writes it)
  bf16* fb16 = (bf16*)d_out;                       // M*512
  bf16* cb16 = fb16 + (size_t)M * 512;             // M*128

  convert_k<<<2048, 256, 0, stream>>>(features, fb16, (long)M * 512);
  convert_k<<<1024, 256, 0, stream>>>(coords, cb16, (long)M * 128);
  transpose_k<<<(512 * 1024 + 255) / 256, 256, 0, stream>>>(w_fqk, wcombT, 512, 1024);
  transpose_k<<<(512 * 512 + 255) / 256, 256, 0, stream>>>(w_v, wcombT + (size_t)1024 * 512, 512, 512);
  transpose_k<<<(128 * 256 + 255) / 256, 256, 0, stream>>>(w_cqk, wcqkT, 128, 256);
  transpose_k<<<(512 * 512 + 255) / 256, 256, 0, stream>>>(w_out, woutT, 512, 512);
  biascat_k<<<6, 256, 0, stream>>>(b_fqk, b_v, bias_comb);

  // fused qk+v projection (+ per-token q|k sumsq partials)
  gemm128_k<bf16, 8><<<dim3(12, 512), 256, 0, stream>>>(fb16, wcombT, bias_comb, qkv, ssq_f, M, 1536, 512);
  // coord projection (+ sumsq partials over all 256 cols)
  gemm128_k<bf16, 2><<<dim3(2, 512), 256, 0, stream>>>(cb16, wcqkT, b_cqk, cqk, ssq_c, M, 256, 128);
  finalize_rs_k<<<TOKENS / 256, 256, 0, stream>>>(ssq_f, ssq_c, rs_f, rs_c);
  attn_mfma_k<<<4 * 16 * 16 * 8, 256, 0, stream>>>(qkv, cqk, pos_emb, g_fqk, g_cqk, rs_f, rs_c, aout);
  gemm128_k<float, 0><<<dim3(4, 512), 256, 0, stream>>>(aout, woutT, b_out, out, nullptr, M, 512, 512);
}

// Round 8
// 385.045 us; speedup vs baseline: 1.0953x; 1.0953x over previous
//
#include <hip/hip_runtime.h>
#include <hip/hip_bf16.h>
#include <type_traits>

using bf16 = __hip_bfloat16;
typedef __bf16 bf16x8 __attribute__((ext_vector_type(8)));
typedef float f32x4 __attribute__((ext_vector_type(4)));

static constexpr int TOKENS = 4 * 128 * 128;  // 65536
#define SCALE_F 0.11180339887498949f          // 1/sqrt(64+16)
#define EPS_F 1e-6f

__device__ __forceinline__ float u2f(unsigned short u) {
  union { unsigned int i; float f; } c; c.i = (unsigned int)u << 16; return c.f;
}
__device__ __forceinline__ unsigned short f2u(float f) {
  bf16 h = __float2bfloat16(f); return *reinterpret_cast<unsigned short*>(&h);
}
__device__ __forceinline__ float b2f(bf16 v) { return __bfloat162float(v); }
__device__ __forceinline__ int4 cvt8(const float* p) {
  float4 a = ((const float4*)p)[0], b = ((const float4*)p)[1];
  union { int4 i4; unsigned short s[8]; } u;
  u.s[0] = f2u(a.x); u.s[1] = f2u(a.y); u.s[2] = f2u(a.z); u.s[3] = f2u(a.w);
  u.s[4] = f2u(b.x); u.s[5] = f2u(b.y); u.s[6] = f2u(b.z); u.s[7] = f2u(b.w);
  return u.i4;
}
__device__ __forceinline__ void gload16(const bf16* g, bf16* l) {
  __builtin_amdgcn_global_load_lds(
      (const __attribute__((address_space(1))) unsigned int*)g,
      (__attribute__((address_space(3))) unsigned int*)l, 16, 0, 0);
}

// ---------------- f32 -> bf16 bulk convert ----------------
__global__ void convert_k(const float* __restrict__ in, bf16* __restrict__ out,
                          long n) {
  long i = ((long)blockIdx.x * 256 + threadIdx.x) * 8;
  long stride = (long)gridDim.x * 256 * 8;
  for (; i < n; i += stride) *(int4*)(out + i) = cvt8(in + i);
}

// ---------------- weight transpose + f32->bf16: out[N][K] = in[K][N] ------
__global__ void transpose_k(const float* __restrict__ in, bf16* __restrict__ out,
                            int K, int N) {
  int i = blockIdx.x * 256 + threadIdx.x;
  if (i >= K * N) return;
  int k = i / N, n = i - k * N;
  out[(size_t)n * K + k] = __float2bfloat16(in[i]);
}

__global__ void biascat_k(const float* __restrict__ a, const float* __restrict__ b,
                          float* __restrict__ o) {
  int i = blockIdx.x * 256 + threadIdx.x;
  if (i < 1536) o[i] = i < 1024 ? a[i] : b[i - 1024];
}

template <int QF>
__device__ __forceinline__ void mfma16(f32x4 (&acc)[8][4], const bf16x8 (&wfr)[4],
                                       const bf16x8 (&xfr)[4]) {
#pragma unroll
  for (int fi = 0; fi < 4; ++fi)
#pragma unroll
    for (int j = 0; j < 4; ++j)
      acc[QF * 4 + fi][j] =
          __builtin_amdgcn_mfma_f32_16x16x32_bf16(wfr[fi], xfr[j], acc[QF * 4 + fi][j], 0, 0, 0);
}

// ------------- 256^2 8-wave phase-split GEMM (T1+T2+T3/T4+T5) -------------
// Tile: 256 tok (bm) x 256 fea (bn), K-tiles of 32. 8 waves = 2(fea wm) x
// 4(tok wn); wave tile 128 fea x 64 tok; acc[8][4] f32x4.
// LDS: sX[3 buf][256 tok][32 k], sW[3 buf][256 fea][32 k] = 96 KB dynamic.
// Per K-tile u (buf u%3): 2 phases:
//   p0: vmcnt(4 | 0@last) ; s_barrier ; stage X_{u+2} ; read X(4)+W(qf0,4) ;
//       setprio1 ; 16 MFMA ; setprio0
//   p1: stage W_{u+2} ; read W(qf1,4) ; setprio1 ; 16 MFMA ; setprio0
// vmcnt ledger: X_u,W_u staged during tile u-2; loads newer = X_{u+1},W_{u+1}
// (4) -> vmcnt(4) confirms them; barrier makes it block-wide before reads.
// Re-stage safety: slot (u+2)%3's old content last read in tile u-1, whose
// MFMAs (hence reads) complete before any wave passes tile-u's barrier.
// T2: chunk ^= (row>>1)&3 on both stage-source and ds_read (2-way, free).
template <typename TC, int SSNX>
__global__ __launch_bounds__(512, 2) void gemm256_k(
    const bf16* __restrict__ A, const bf16* __restrict__ Wt,
    const float* __restrict__ bias, TC* __restrict__ C,
    float* __restrict__ ssq, int M, int N, int K) {
  extern __shared__ __align__(16) bf16 smem[];
  bf16* sX = smem;            // 3*8192 elems
  bf16* sW = smem + 24576;
  const int t = threadIdx.x, lane = t & 63, wave = t >> 6;
  const int wm = wave >> 2, wn = wave & 3;
  const int l15 = lane & 15, kg = lane >> 4;
  const int nwg = gridDim.x * gridDim.y;
  int id = blockIdx.y * gridDim.x + blockIdx.x;
  id = (id & 7) * (nwg >> 3) + (id >> 3);          // T1 (nwg % 8 == 0)
  const int bx = id % gridDim.x, by = id / gridDim.x;
  const int bm = by * 256, bn = bx * 256;
  f32x4 acc[8][4] = {};

  const int srow = t >> 2;                              // 0..127
  const int sw8 = ((t & 3) ^ ((srow >> 1) & 3)) * 8;    // pre-swizzled src chunk
  const int sdst = srow * 32 + (t & 3) * 8;             // linear LDS dest
  const int fsw = (kg ^ ((l15 >> 1) & 3)) * 8;          // swizzled read chunk

  auto stageX = [&](int buf, int k0) {
    bf16* d = sX + buf * 8192 + sdst;
    gload16(A + (size_t)(bm + srow) * K + k0 + sw8, d);
    gload16(A + (size_t)(bm + 128 + srow) * K + k0 + sw8, d + 4096);
  };
  auto stageW = [&](int buf, int k0) {
    bf16* d = sW + buf * 8192 + sdst;
    gload16(Wt + (size_t)(bn + srow) * K + k0 + sw8, d);
    gload16(Wt + (size_t)(bn + 128 + srow) * K + k0 + sw8, d + 4096);
  };

  const int NT = K >> 5;
  stageX(0, 0); stageW(0, 0); stageX(1, 32); stageW(1, 32);

  int buf = 0;
  for (int u = 0; u < NT; ++u) {
    if (u < NT - 1) asm volatile("s_waitcnt vmcnt(4)" ::: "memory");
    else            asm volatile("s_waitcnt vmcnt(0)" ::: "memory");
    __builtin_amdgcn_s_barrier();
    __builtin_amdgcn_sched_barrier(0);
    int nb = buf + 2; if (nb >= 3) nb -= 3;
    if (u + 2 < NT) stageX(nb, (u + 2) * 32);
    bf16x8 xfr[4], wfr[4];
    const bf16* bX = sX + buf * 8192;
    const bf16* bW = sW + buf * 8192;
#pragma unroll
    for (int j = 0; j < 4; ++j)
      xfr[j] = *(const bf16x8*)(bX + (wn * 64 + j * 16 + l15) * 32 + fsw);
#pragma unroll
    for (int fi = 0; fi < 4; ++fi)
      wfr[fi] = *(const bf16x8*)(bW + (wm * 128 + fi * 16 + l15) * 32 + fsw);
    __builtin_amdgcn_s_setprio(1);
    mfma16<0>(acc, wfr, xfr);
    __builtin_amdgcn_s_setprio(0);
    // p1
    if (u + 2 < NT) stageW(nb, (u + 2) * 32);
#pragma unroll
    for (int fi = 0; fi < 4; ++fi)
      wfr[fi] = *(const bf16x8*)(bW + (wm * 128 + 64 + fi * 16 + l15) * 32 + fsw);
    __builtin_amdgcn_s_setprio(1);
    mfma16<1>(acc, wfr, xfr);
    __builtin_amdgcn_s_setprio(0);
    buf = (buf == 2) ? 0 : buf + 1;
  }

  // epilogue: feat = bn + wm*128 + (i>>2)*64 + (i&3)*16 + kg*4 + r
  //           token = bm + wn*64 + j*16 + l15
  float bvi[8][4];
#pragma unroll
  for (int i = 0; i < 8; ++i) {
    float4 b4 = *(const float4*)(bias + bn + wm * 128 + (i >> 2) * 64 + (i & 3) * 16 + kg * 4);
    bvi[i][0] = b4.x; bvi[i][1] = b4.y; bvi[i][2] = b4.z; bvi[i][3] = b4.w;
  }
#pragma unroll
  for (int j = 0; j < 4; ++j) {
    const int token = bm + wn * 64 + j * 16 + l15;
    float ssum = 0.f;
#pragma unroll
    for (int i = 0; i < 8; ++i) {
      float v0 = acc[i][j][0] + bvi[i][0];
      float v1 = acc[i][j][1] + bvi[i][1];
      float v2 = acc[i][j][2] + bvi[i][2];
      float v3 = acc[i][j][3] + bvi[i][3];
      const size_t off = (size_t)token * N + bn + wm * 128 + (i >> 2) * 64 + (i & 3) * 16 + kg * 4;
      if constexpr (std::is_same<TC, float>::value) {
        *(float4*)(C + off) = float4{v0, v1, v2, v3};
      } else {
        ushort4 pk{f2u(v0), f2u(v1), f2u(v2), f2u(v3)};
        *(ushort4*)(C + off) = pk;
      }
      if constexpr (SSNX > 0)
        ssum += v0 * v0 + v1 * v1 + v2 * v2 + v3 * v3;
    }
    if constexpr (SSNX > 0) {
      ssum += __shfl_xor(ssum, 16);
      ssum += __shfl_xor(ssum, 32);
      if (bx < SSNX && kg == 0)
        ssq[(size_t)token * (SSNX * 2) + bx * 2 + wm] = ssum;
    }
  }
}

// ---------------- 128^2 GEMM (R6 structure) for the small cqk GEMM --------
template <typename TC, int SSNX>
__global__ __launch_bounds__(256) void gemm128_k(
    const bf16* __restrict__ A, const bf16* __restrict__ Wt,
    const float* __restrict__ bias, TC* __restrict__ C,
    float* __restrict__ ssq, int M, int N, int K) {
  __shared__ __align__(16) bf16 sA[2][4096];
  __shared__ __align__(16) bf16 sB[2][4096];
  const int t = threadIdx.x, lane = t & 63, wave = t >> 6;
  const int wr = wave >> 1, wc = wave & 1;
  const int nwg = gridDim.x * gridDim.y;
  int id = blockIdx.y * gridDim.x + blockIdx.x;
  if ((nwg & 7) == 0) id = (id & 7) * (nwg >> 3) + (id >> 3);
  const int bx = id % gridDim.x, by = id / gridDim.x;
  const int bm = by * 128, bn = bx * 128;
  const int l15 = lane & 15, kg = lane >> 4;
  f32x4 acc[4][4] = {};

  const int srow = t >> 2;
  const int ske = ((t & 3) ^ ((srow >> 1) & 3)) * 8;
  const bf16* pA0 = A + (size_t)(bm + srow) * K + ske;
  const bf16* pA1 = A + (size_t)(bm + 64 + srow) * K + ske;
  const bf16* pB0 = Wt + (size_t)(bn + srow) * K + ske;
  const bf16* pB1 = Wt + (size_t)(bn + 64 + srow) * K + ske;
  const int wo = wave * 512;

  gload16(pA0, &sA[0][wo]);
  gload16(pA1, &sA[0][2048 + wo]);
  gload16(pB0, &sB[0][wo]);
  gload16(pB1, &sB[0][2048 + wo]);
  __syncthreads();

  const int nt = K >> 5;
  int cur = 0;
  for (int tt = 0; tt < nt; ++tt) {
    if (tt + 1 < nt) {
      pA0 += 32; pA1 += 32; pB0 += 32; pB1 += 32;
      gload16(pA0, &sA[cur ^ 1][wo]);
      gload16(pA1, &sA[cur ^ 1][2048 + wo]);
      gload16(pB0, &sB[cur ^ 1][wo]);
      gload16(pB1, &sB[cur ^ 1][2048 + wo]);
    }
    bf16x8 wf[4], xf[4];
#pragma unroll
    for (int i = 0; i < 4; ++i) {
      int frow = wc * 64 + i * 16 + l15;
      int xrow = wr * 64 + i * 16 + l15;
      wf[i] = *(const bf16x8*)(&sB[cur][frow * 32 + ((kg ^ ((frow >> 1) & 3)) * 8)]);
      xf[i] = *(const bf16x8*)(&sA[cur][xrow * 32 + ((kg ^ ((xrow >> 1) & 3)) * 8)]);
    }
#pragma unroll
    for (int i = 0; i < 4; ++i)
#pragma unroll
      for (int j = 0; j < 4; ++j)
        acc[i][j] = __builtin_amdgcn_mfma_f32_16x16x32_bf16(wf[i], xf[j], acc[i][j], 0, 0, 0);
    __syncthreads();
    cur ^= 1;
  }

  float bvi[4][4];
#pragma unroll
  for (int i = 0; i < 4; ++i) {
    float4 b4 = *(const float4*)(bias + bn + wc * 64 + i * 16 + kg * 4);
    bvi[i][0] = b4.x; bvi[i][1] = b4.y; bvi[i][2] = b4.z; bvi[i][3] = b4.w;
  }
#pragma unroll
  for (int j = 0; j < 4; ++j) {
    const int token = bm + wr * 64 + j * 16 + l15;
    float ssum = 0.f;
#pragma unroll
    for (int i = 0; i < 4; ++i) {
      float v0 = acc[i][j][0] + bvi[i][0];
      float v1 = acc[i][j][1] + bvi[i][1];
      float v2 = acc[i][j][2] + bvi[i][2];
      float v3 = acc[i][j][3] + bvi[i][3];
      const size_t off = (size_t)token * N + bn + wc * 64 + i * 16 + kg * 4;
      if constexpr (std::is_same<TC, float>::value) {
        *(float4*)(C + off) = float4{v0, v1, v2, v3};
      } else {
        ushort4 pk{f2u(v0), f2u(v1), f2u(v2), f2u(v3)};
        *(ushort4*)(C + off) = pk;
      }
      if constexpr (SSNX > 0)
        ssum += v0 * v0 + v1 * v1 + v2 * v2 + v3 * v3;
    }
    if constexpr (SSNX > 0) {
      ssum += __shfl_xor(ssum, 16);
      ssum += __shfl_xor(ssum, 32);
      if (bx < SSNX && kg == 0)
        ssq[(size_t)token * (SSNX * 2) + bx * 2 + wc] = ssum;
    }
  }
}

// ---------------- finalize: partial sumsq -> per-token rsqrt scales -------
__global__ void finalize_rs_k(const float* __restrict__ pf,
                              const float* __restrict__ pc,
                              float* __restrict__ rsf, float* __restrict__ rsc) {
  int i = blockIdx.x * 256 + threadIdx.x;
  if (i >= TOKENS) return;
  float s = 0.f;
#pragma unroll
  for (int j = 0; j < 8; ++j) s += pf[(size_t)i * 8 + j];
  rsf[i] = rsqrtf(s * (1.f / 1024.f) + EPS_F);
  float c = 0.f;
#pragma unroll
  for (int j = 0; j < 4; ++j) c += pc[(size_t)i * 4 + j];
  rsc[i] = rsqrtf(c * (1.f / 256.f) + EPS_F);
}

// ---------------- MFMA windowed attention: one block per (window, head) ---
__global__ __launch_bounds__(256) void attn_mfma_k(
    const bf16* __restrict__ qkv, const bf16* __restrict__ cqk,
    const float* __restrict__ pos, const float* __restrict__ g_fqk,
    const float* __restrict__ g_cqk, const float* __restrict__ rs_f,
    const float* __restrict__ rs_c, bf16* __restrict__ aout) {
  __shared__ __align__(16) bf16 sQ[64][104], sK[64][104];
  __shared__ __align__(16) bf16 sVt[64][72];
  __shared__ __align__(16) bf16 sP[64][72];
  __shared__ float sPos[15][15];
  __shared__ float sRsF[64], sRsC[64];
  const int t = threadIdx.x, lane = t & 63, wave = t >> 6;
  const int head = blockIdx.x & 7;
  const int wid = blockIdx.x >> 3;
  const int wx = wid & 15, wy = (wid >> 4) & 15, b = wid >> 8;

  for (int i = t; i < 225; i += 256) sPos[i / 15][i % 15] = pos[i];
  if (t < 64) {
    const int y = ((wy << 3) + (t >> 3) + 4) & 127;
    const int x = ((wx << 3) + (t & 7) + 4) & 127;
    const size_t tok = ((size_t)b << 14) | (y << 7) | x;
    sRsF[t] = rs_f[tok];
    sRsC[t] = rs_c[tok];
  }
  {
    const int n = t >> 2, p = t & 3;
    const int y = ((wy << 3) + (n >> 3) + 4) & 127;
    const int x = ((wx << 3) + (n & 7) + 4) & 127;
    const size_t tok = ((size_t)b << 14) | (y << 7) | x;
    const bf16* row = qkv + tok * 1536;
    const int4* qp = (const int4*)(row + head * 64 + p * 16);
    ((int4*)&sQ[n][p * 16])[0] = qp[0];
    ((int4*)&sQ[n][p * 16])[1] = qp[1];
    {
      const bf16* kpp = row + 512 + head * 64 + p * 16;
      const float* gq = g_fqk + head * 64 + p * 16;
      const float* gk = g_fqk + 512 + head * 64 + p * 16;
      union { int4 v[2]; unsigned short s[16]; } kt;
#pragma unroll
      for (int i = 0; i < 16; ++i)
        kt.s[i] = f2u(b2f(kpp[i]) * gq[i] * gk[i]);
      ((int4*)&sK[n][p * 16])[0] = kt.v[0];
      ((int4*)&sK[n][p * 16])[1] = kt.v[1];
    }
    const bf16* vp = row + 1024 + head * 64 + p * 16;
#pragma unroll
    for (int i = 0; i < 16; ++i) sVt[p * 16 + i][n] = vp[i];
    const bf16* crow = cqk + tok * 256;
    if (p == 0) {
      const int4* cp = (const int4*)(crow + head * 16);
      ((int4*)&sQ[n][64])[0] = cp[0];
      ((int4*)&sQ[n][64])[1] = cp[1];
    } else if (p == 1) {
      const bf16* ckp = crow + 128 + head * 16;
      const float* gcq = g_cqk + head * 16;
      const float* gck = g_cqk + 128 + head * 16;
      union { int4 v[2]; unsigned short s[16]; } ct;
#pragma unroll
      for (int i = 0; i < 16; ++i)
        ct.s[i] = f2u(b2f(ckp[i]) * gcq[i] * gck[i]);
      ((int4*)&sK[n][64])[0] = ct.v[0];
      ((int4*)&sK[n][64])[1] = ct.v[1];
    } else if (p == 2) {
      ((int4*)&sQ[n][80])[0] = int4{0, 0, 0, 0};
      ((int4*)&sQ[n][80])[1] = int4{0, 0, 0, 0};
    } else {
      ((int4*)&sK[n][80])[0] = int4{0, 0, 0, 0};
      ((int4*)&sK[n][80])[1] = int4{0, 0, 0, 0};
    }
  }
  __syncthreads();

  const int l15 = lane & 15, kg = lane >> 4;
  bf16x8 qa[3];
#pragma unroll
  for (int ko = 0; ko < 3; ++ko)
    qa[ko] = *(const bf16x8*)&sQ[wave * 16 + l15][ko * 32 + kg * 8];
  f32x4 saccf[4] = {}, saccc[4] = {};
#pragma unroll
  for (int j = 0; j < 4; ++j) {
#pragma unroll
    for (int ko = 0; ko < 2; ++ko) {
      bf16x8 kb = *(const bf16x8*)&sK[j * 16 + l15][ko * 32 + kg * 8];
      saccf[j] = __builtin_amdgcn_mfma_f32_16x16x32_bf16(qa[ko], kb, saccf[j], 0, 0, 0);
    }
    bf16x8 kb2 = *(const bf16x8*)&sK[j * 16 + l15][64 + kg * 8];
    saccc[j] = __builtin_amdgcn_mfma_f32_16x16x32_bf16(qa[2], kb2, saccc[j], 0, 0, 0);
  }

  const bool lastx = (wx == 15), lasty = (wy == 15);
  float rqf[4], rqc[4];
#pragma unroll
  for (int r = 0; r < 4; ++r) {
    rqf[r] = sRsF[wave * 16 + kg * 4 + r];
    rqc[r] = sRsC[wave * 16 + kg * 4 + r];
  }
  float sv[4][4], mx[4], sum[4], inv[4];
#pragma unroll
  for (int r = 0; r < 4; ++r) mx[r] = -1e30f;
#pragma unroll
  for (int j = 0; j < 4; ++j) {
    int kcol = j * 16 + l15, kh = kcol >> 3, kw = kcol & 7;
    float rkf = sRsF[kcol], rkc = sRsC[kcol];
#pragma unroll
    for (int r = 0; r < 4; ++r) {
      int q = wave * 16 + kg * 4 + r, qh = q >> 3, qw = q & 7;
      bool msk = (lastx && ((qh >= 4) != (kh >= 4))) ||
                 (lasty && ((qw >= 4) != (kw >= 4)));
      float raw = saccf[j][r] * rqf[r] * rkf + saccc[j][r] * rqc[r] * rkc;
      float val = msk ? -1e30f : raw * SCALE_F + sPos[kh - qh + 7][kw - qw + 7];
      sv[j][r] = val;
      mx[r] = fmaxf(mx[r], val);
    }
  }
#pragma unroll
  for (int m = 1; m < 16; m <<= 1)
#pragma unroll
    for (int r = 0; r < 4; ++r) mx[r] = fmaxf(mx[r], __shfl_xor(mx[r], m));
#pragma unroll
  for (int r = 0; r < 4; ++r) sum[r] = 0.f;
#pragma unroll
  for (int j = 0; j < 4; ++j) {
    int kcol = j * 16 + l15;
#pragma unroll
    for (int r = 0; r < 4; ++r) {
      float e = __expf(sv[j][r] - mx[r]);
      sum[r] += e;
      sP[wave * 16 + kg * 4 + r][kcol] = __float2bfloat16(e);
    }
  }
#pragma unroll
  for (int m = 1; m < 16; m <<= 1)
#pragma unroll
    for (int r = 0; r < 4; ++r) sum[r] += __shfl_xor(sum[r], m);
#pragma unroll
  for (int r = 0; r < 4; ++r) inv[r] = 1.f / sum[r];
  __syncthreads();

  bf16x8 pa[2];
#pragma unroll
  for (int ko = 0; ko < 2; ++ko)
    pa[ko] = *(const bf16x8*)&sP[wave * 16 + l15][ko * 32 + kg * 8];
  f32x4 oacc[4] = {};
#pragma unroll
  for (int jf = 0; jf < 4; ++jf)
#pragma unroll
    for (int ko = 0; ko < 2; ++ko) {
      bf16x8 vb = *(const bf16x8*)&sVt[jf * 16 + l15][ko * 32 + kg * 8];
      oacc[jf] = __builtin_amdgcn_mfma_f32_16x16x32_bf16(pa[ko], vb, oacc[jf], 0, 0, 0);
    }
#pragma unroll
  for (int r = 0; r < 4; ++r) {
    int q = wave * 16 + kg * 4 + r;
    const int y = ((wy << 3) + (q >> 3) + 4) & 127;
    const int x = ((wx << 3) + (q & 7) + 4) & 127;
    const size_t tok = ((size_t)b << 14) | (y << 7) | x;
    bf16* dst = aout + tok * 512 + head * 64;
#pragma unroll
    for (int jf = 0; jf < 4; ++jf)
      dst[jf * 16 + l15] = __float2bfloat16(oacc[jf][r] * inv[r]);
  }
}

extern "C" void kernel_launch(void* const* d_in, const int* in_sizes, int n_in,
                              void* d_out, int out_size, void* d_ws, size_t ws_size,
                              hipStream_t stream) {
  const float* features = (const float*)d_in[0];
  const float* coords   = (const float*)d_in[1];
  const float* w_fqk = (const float*)d_in[2];
  const float* b_fqk = (const float*)d_in[3];
  const float* g_fqk = (const float*)d_in[4];
  const float* w_cqk = (const float*)d_in[5];
  const float* b_cqk = (const float*)d_in[6];
  const float* g_cqk = (const float*)d_in[7];
  const float* w_v   = (const float*)d_in[8];
  const float* b_v   = (const float*)d_in[9];
  const float* w_out = (const float*)d_in[10];
  const float* b_out = (const float*)d_in[11];
  const float* pos_emb = (const float*)d_in[12];
  float* out = (float*)d_out;

  const int M = TOKENS;  // 65536
  bf16* qkv   = (bf16*)d_ws;                       // M*1536 (raw q|k|v)
  bf16* cqk   = qkv + (size_t)M * 1536;            // M*256 (raw cq|ck)
  bf16* aout  = cqk + (size_t)M * 256;             // M*512
  bf16* wcombT = aout + (size_t)M * 512;           // 1536*512
  bf16* wcqkT  = wcombT + (size_t)1536 * 512;      // 256*128
  bf16* woutT  = wcqkT + 256 * 128;                // 512*512
  float* bias_comb = (float*)(woutT + 512 * 512);  // 1536 f32
  float* ssq_f = bias_comb + 1536;                 // M*8 f32
  float* ssq_c = ssq_f + (size_t)M * 8;            // M*4 f32
  float* rs_f  = ssq_c + (size_t)M * 4;            // M f32
  float* rs_c  = rs_f + M;                         // M f32
  bf16* fb16 = (bf16*)d_out;                       // M*512 (aliased, dead)
  bf16* cb16 = fb16 + (size_t)M * 512;             // M*128

  convert_k<<<2048, 256, 0, stream>>>(features, fb16, (long)M * 512);
  convert_k<<<1024, 256, 0, stream>>>(coords, cb16, (long)M * 128);
  transpose_k<<<(512 * 1024 + 255) / 256, 256, 0, stream>>>(w_fqk, wcombT, 512, 1024);
  transpose_k<<<(512 * 512 + 255) / 256, 256, 0, stream>>>(w_v, wcombT + (size_t)1024 * 512, 512, 512);
  transpose_k<<<(128 * 256 + 255) / 256, 256, 0, stream>>>(w_cqk, wcqkT, 128, 256);
  transpose_k<<<(512 * 512 + 255) / 256, 256, 0, stream>>>(w_out, woutT, 512, 512);
  biascat_k<<<6, 256, 0, stream>>>(b_fqk, b_v, bias_comb);

  // fused qk+v projection (256^2 8-wave pipeline; + q|k sumsq partials)
  gemm256_k<bf16, 4><<<dim3(6, 256), 512, 98304, stream>>>(fb16, wcombT, bias_comb, qkv, ssq_f, M, 1536, 512);
  // coord projection (small: keep 128^2 kernel)
  gemm128_k<bf16, 2><<<dim3(2, 512), 256, 0, stream>>>(cb16, wcqkT, b_cqk, cqk, ssq_c, M, 256, 128);
  finalize_rs_k<<<TOKENS / 256, 256, 0, stream>>>(ssq_f, ssq_c, rs_f, rs_c);
  attn_mfma_k<<<4 * 16 * 16 * 8, 256, 0, stream>>>(qkv, cqk, pos_emb, g_fqk, g_cqk, rs_f, rs_c, aout);
  // output projection (256^2 pipeline, f32 out)
  gemm256_k<float, 0><<<dim3(2, 256), 512, 98304, stream>>>(aout, woutT, b_out, out, nullptr, M, 512, 512);
}

// Round 9
// 374.870 us; speedup vs baseline: 1.1251x; 1.0271x over previous
//
#include <hip/hip_runtime.h>
#include <hip/hip_bf16.h>
#include <type_traits>

using bf16 = __hip_bfloat16;
typedef __bf16 bf16x8 __attribute__((ext_vector_type(8)));
typedef float f32x4 __attribute__((ext_vector_type(4)));

static constexpr int TOKENS = 4 * 128 * 128;  // 65536
#define SCALE_F 0.11180339887498949f          // 1/sqrt(64+16)
#define EPS_F 1e-6f

__device__ __forceinline__ float u2f(unsigned short u) {
  union { unsigned int i; float f; } c; c.i = (unsigned int)u << 16; return c.f;
}
__device__ __forceinline__ unsigned short f2u(float f) {
  bf16 h = __float2bfloat16(f); return *reinterpret_cast<unsigned short*>(&h);
}
__device__ __forceinline__ float b2f(bf16 v) { return __bfloat162float(v); }
__device__ __forceinline__ int4 cvt8(const float* p) {
  float4 a = ((const float4*)p)[0], b = ((const float4*)p)[1];
  union { int4 i4; unsigned short s[8]; } u;
  u.s[0] = f2u(a.x); u.s[1] = f2u(a.y); u.s[2] = f2u(a.z); u.s[3] = f2u(a.w);
  u.s[4] = f2u(b.x); u.s[5] = f2u(b.y); u.s[6] = f2u(b.z); u.s[7] = f2u(b.w);
  return u.i4;
}
__device__ __forceinline__ void gload16(const bf16* g, bf16* l) {
  __builtin_amdgcn_global_load_lds(
      (const __attribute__((address_space(1))) unsigned int*)g,
      (__attribute__((address_space(3))) unsigned int*)l, 16, 0, 0);
}

// ---------------- f32 -> bf16 bulk convert ----------------
__global__ void convert_k(const float* __restrict__ in, bf16* __restrict__ out,
                          long n) {
  long i = ((long)blockIdx.x * 256 + threadIdx.x) * 8;
  long stride = (long)gridDim.x * 256 * 8;
  for (; i < n; i += stride) *(int4*)(out + i) = cvt8(in + i);
}

// ---------------- weight transpose + f32->bf16: out[N][K] = in[K][N] ------
__global__ void transpose_k(const float* __restrict__ in, bf16* __restrict__ out,
                            int K, int N) {
  int i = blockIdx.x * 256 + threadIdx.x;
  if (i >= K * N) return;
  int k = i / N, n = i - k * N;
  out[(size_t)n * K + k] = __float2bfloat16(in[i]);
}

__global__ void biascat_k(const float* __restrict__ a, const float* __restrict__ b,
                          float* __restrict__ o) {
  int i = blockIdx.x * 256 + threadIdx.x;
  if (i < 1536) o[i] = i < 1024 ? a[i] : b[i - 1024];
}

// ------------- 256^2 4-phase/K-tile GEMM (m201-template adaptation) -------
// BM=256 tok x BN=256 fea, BK=64, 8 waves (2 wm x 4 wn), wave = 128fea x
// 64tok. Per K-tile u (buf u&1), 4 phases = C-quadrants Q00,Q01,Q10,Q11:
//   A: vmcnt(4); bar; read W[fh0](8)+X[th0](4); stage W0,X0(u+1)[4 gl];
//      lgkm0; prio1; 16 MFMA; prio0
//   B: vmcnt(6|2); bar; read X[th1](4); stage X1(u+1)[2]; ... 16 MFMA
//   C: vmcnt(6|0); bar; read W[fh1](8); stage W1(u+1)[2]; ... 16 MFMA
//   D: bar; 16 MFMA (all regs live)
// Halves are CONSUMPTION-aligned in LDS: W LDS row' = fh*128+wm*64+r,
// X row' = th*128+wn*32+s, so each staged half is exactly one phase's bytes
// for all waves. Stage->use distance = 4 phases for every half; vmcnt never
// 0 mid-loop (T4). Overwrite of buf^1 region is >=4 barriers after its last
// reader's lgkmcnt(0). T2 swizzle: chunk ^= row&7 (both sides). T1 swizzle.
template <typename TC, int SSNX>
__global__ __launch_bounds__(512, 2) void gemm256p_k(
    const bf16* __restrict__ A, const bf16* __restrict__ Wt,
    const float* __restrict__ bias, TC* __restrict__ C,
    float* __restrict__ ssq, int M, int N, int K) {
  extern __shared__ __align__(16) bf16 smem[];
  bf16* sW = smem;            // 2 buf x [256 fea][64 k] = 64KB
  bf16* sX = smem + 32768;    // 2 buf x [256 tok][64 k] = 64KB
  const int t = threadIdx.x, lane = t & 63, wave = t >> 6;
  const int wm = wave >> 2, wn = wave & 3;
  const int l15 = lane & 15, kg = lane >> 4;
  const int nwg = gridDim.x * gridDim.y;
  int id = blockIdx.y * gridDim.x + blockIdx.x;
  id = (id & 7) * (nwg >> 3) + (id >> 3);          // T1 (nwg % 8 == 0)
  const int bx = id % gridDim.x, by = id / gridDim.x;
  const int bm = by * 256, bn = bx * 256;
  f32x4 acc[8][4] = {};

  const int lr = t >> 3, ch = t & 7;               // staging row/chunk
  const int ssw = ((ch ^ (lr & 7)) * 8);           // pre-swizzled src chunk
  const int rsw = (l15 & 7) * 8;                   // read-side swizzle term

  auto stW = [&](int buf, int fh, int k0) {
#pragma unroll
    for (int g = 0; g < 2; ++g)
      gload16(Wt + (size_t)(bn + g * 128 + fh * 64 + lr) * K + k0 + ssw,
              sW + buf * 16384 + (fh * 128 + g * 64) * 64 + t * 8);
  };
  auto stX = [&](int buf, int th, int k0) {
#pragma unroll
    for (int g = 0; g < 2; ++g)
      gload16(A + (size_t)(bm + (g * 2 + (lr >> 5)) * 64 + th * 32 + (lr & 31)) * K + k0 + ssw,
              sX + buf * 16384 + (th * 128 + g * 64) * 64 + t * 8);
  };
  auto rdW = [&](int buf, int fh, int i, int ks) {
    int row = fh * 128 + wm * 64 + i * 16 + l15;
    return *(const bf16x8*)(sW + buf * 16384 + row * 64 + ((ks * 32 + kg * 8) ^ rsw));
  };
  auto rdX = [&](int buf, int th, int j, int ks) {
    int row = th * 128 + wn * 32 + j * 16 + l15;
    return *(const bf16x8*)(sX + buf * 16384 + row * 64 + ((ks * 32 + kg * 8) ^ rsw));
  };

  const int NT = K >> 6;  // BK=64
  // prologue: tile 0 -> buf 0, in steady-state issue order
  stW(0, 0, 0); stX(0, 0, 0); stX(0, 1, 0); stW(0, 1, 0);

  bf16x8 wfr[4][2], xf0[2][2], xf1[2][2];
  for (int u = 0; u < NT; ++u) {
    const int buf = u & 1, nbuf = buf ^ 1, k1 = (u + 1) << 6;
    const bool pf = (u + 1 < NT);
    // ---------------- phase A : Q00 ----------------
    asm volatile("s_waitcnt vmcnt(4)" ::: "memory");
    __builtin_amdgcn_s_barrier();
    __builtin_amdgcn_sched_barrier(0);
#pragma unroll
    for (int i = 0; i < 4; ++i)
#pragma unroll
      for (int ks = 0; ks < 2; ++ks) wfr[i][ks] = rdW(buf, 0, i, ks);
#pragma unroll
    for (int j = 0; j < 2; ++j)
#pragma unroll
      for (int ks = 0; ks < 2; ++ks) xf0[j][ks] = rdX(buf, 0, j, ks);
    if (pf) { stW(nbuf, 0, k1); stX(nbuf, 0, k1); }
    asm volatile("s_waitcnt lgkmcnt(0)" ::: "memory");
    __builtin_amdgcn_sched_barrier(0);
    __builtin_amdgcn_s_setprio(1);
#pragma unroll
    for (int i = 0; i < 4; ++i)
#pragma unroll
      for (int j = 0; j < 2; ++j)
#pragma unroll
        for (int ks = 0; ks < 2; ++ks)
          acc[i][j] = __builtin_amdgcn_mfma_f32_16x16x32_bf16(wfr[i][ks], xf0[j][ks], acc[i][j], 0, 0, 0);
    __builtin_amdgcn_s_setprio(0);
    // ---------------- phase B : Q01 ----------------
    if (pf) asm volatile("s_waitcnt vmcnt(6)" ::: "memory");
    else    asm volatile("s_waitcnt vmcnt(2)" ::: "memory");
    __builtin_amdgcn_s_barrier();
    __builtin_amdgcn_sched_barrier(0);
#pragma unroll
    for (int j = 0; j < 2; ++j)
#pragma unroll
      for (int ks = 0; ks < 2; ++ks) xf1[j][ks] = rdX(buf, 1, j, ks);
    if (pf) stX(nbuf, 1, k1);
    asm volatile("s_waitcnt lgkmcnt(0)" ::: "memory");
    __builtin_amdgcn_sched_barrier(0);
    __builtin_amdgcn_s_setprio(1);
#pragma unroll
    for (int i = 0; i < 4; ++i)
#pragma unroll
      for (int j = 0; j < 2; ++j)
#pragma unroll
        for (int ks = 0; ks < 2; ++ks)
          acc[i][2 + j] = __builtin_amdgcn_mfma_f32_16x16x32_bf16(wfr[i][ks], xf1[j][ks], acc[i][2 + j], 0, 0, 0);
    __builtin_amdgcn_s_setprio(0);
    // ---------------- phase C : Q10 ----------------
    if (pf) asm volatile("s_waitcnt vmcnt(6)" ::: "memory");
    else    asm volatile("s_waitcnt vmcnt(0)" ::: "memory");
    __builtin_amdgcn_s_barrier();
    __builtin_amdgcn_sched_barrier(0);
#pragma unroll
    for (int i = 0; i < 4; ++i)
#pragma unroll
      for (int ks = 0; ks < 2; ++ks) wfr[i][ks] = rdW(buf, 1, i, ks);
    if (pf) stW(nbuf, 1, k1);
    asm volatile("s_waitcnt lgkmcnt(0)" ::: "memory");
    __builtin_amdgcn_sched_barrier(0);
    __builtin_amdgcn_s_setprio(1);
#pragma unroll
    for (int i = 0; i < 4; ++i)
#pragma unroll
      for (int j = 0; j < 2; ++j)
#pragma unroll
        for (int ks = 0; ks < 2; ++ks)
          acc[4 + i][j] = __builtin_amdgcn_mfma_f32_16x16x32_bf16(wfr[i][ks], xf0[j][ks], acc[4 + i][j], 0, 0, 0);
    __builtin_amdgcn_s_setprio(0);
    // ---------------- phase D : Q11 ----------------
    __builtin_amdgcn_s_barrier();
    __builtin_amdgcn_sched_barrier(0);
    __builtin_amdgcn_s_setprio(1);
#pragma unroll
    for (int i = 0; i < 4; ++i)
#pragma unroll
      for (int j = 0; j < 2; ++j)
#pragma unroll
        for (int ks = 0; ks < 2; ++ks)
          acc[4 + i][2 + j] = __builtin_amdgcn_mfma_f32_16x16x32_bf16(wfr[i][ks], xf1[j][ks], acc[4 + i][2 + j], 0, 0, 0);
    __builtin_amdgcn_s_setprio(0);
  }

  // epilogue: feature = bn + wm*128 + (fi>>2)*64 + (fi&3)*16 + kg*4 + r
  //           token   = bm + wn*64 + (tj>>1)*32 + (tj&1)*16 + l15
  float bvi[8][4];
#pragma unroll
  for (int fi = 0; fi < 8; ++fi) {
    float4 b4 = *(const float4*)(bias + bn + wm * 128 + (fi >> 2) * 64 + (fi & 3) * 16 + kg * 4);
    bvi[fi][0] = b4.x; bvi[fi][1] = b4.y; bvi[fi][2] = b4.z; bvi[fi][3] = b4.w;
  }
#pragma unroll
  for (int tj = 0; tj < 4; ++tj) {
    const int token = bm + wn * 64 + (tj >> 1) * 32 + (tj & 1) * 16 + l15;
    float ssum = 0.f;
#pragma unroll
    for (int fi = 0; fi < 8; ++fi) {
      float v0 = acc[fi][tj][0] + bvi[fi][0];
      float v1 = acc[fi][tj][1] + bvi[fi][1];
      float v2 = acc[fi][tj][2] + bvi[fi][2];
      float v3 = acc[fi][tj][3] + bvi[fi][3];
      const size_t off = (size_t)token * N + bn + wm * 128 + (fi >> 2) * 64 + (fi & 3) * 16 + kg * 4;
      if constexpr (std::is_same<TC, float>::value) {
        *(float4*)(C + off) = float4{v0, v1, v2, v3};
      } else {
        ushort4 pk{f2u(v0), f2u(v1), f2u(v2), f2u(v3)};
        *(ushort4*)(C + off) = pk;
      }
      if constexpr (SSNX > 0)
        ssum += v0 * v0 + v1 * v1 + v2 * v2 + v3 * v3;
    }
    if constexpr (SSNX > 0) {
      ssum += __shfl_xor(ssum, 16);
      ssum += __shfl_xor(ssum, 32);
      if (bx < SSNX && kg == 0)
        ssq[(size_t)token * (SSNX * 2) + bx * 2 + wm] = ssum;
    }
  }
}

// ---------------- 128^2 GEMM (R6 structure) for the small cqk GEMM --------
template <typename TC, int SSNX>
__global__ __launch_bounds__(256) void gemm128_k(
    const bf16* __restrict__ A, const bf16* __restrict__ Wt,
    const float* __restrict__ bias, TC* __restrict__ C,
    float* __restrict__ ssq, int M, int N, int K) {
  __shared__ __align__(16) bf16 sA[2][4096];
  __shared__ __align__(16) bf16 sB[2][4096];
  const int t = threadIdx.x, lane = t & 63, wave = t >> 6;
  const int wr = wave >> 1, wc = wave & 1;
  const int nwg = gridDim.x * gridDim.y;
  int id = blockIdx.y * gridDim.x + blockIdx.x;
  if ((nwg & 7) == 0) id = (id & 7) * (nwg >> 3) + (id >> 3);
  const int bx = id % gridDim.x, by = id / gridDim.x;
  const int bm = by * 128, bn = bx * 128;
  const int l15 = lane & 15, kg = lane >> 4;
  f32x4 acc[4][4] = {};

  const int srow = t >> 2;
  const int ske = ((t & 3) ^ ((srow >> 1) & 3)) * 8;
  const bf16* pA0 = A + (size_t)(bm + srow) * K + ske;
  const bf16* pA1 = A + (size_t)(bm + 64 + srow) * K + ske;
  const bf16* pB0 = Wt + (size_t)(bn + srow) * K + ske;
  const bf16* pB1 = Wt + (size_t)(bn + 64 + srow) * K + ske;
  const int wo = wave * 512;

  gload16(pA0, &sA[0][wo]);
  gload16(pA1, &sA[0][2048 + wo]);
  gload16(pB0, &sB[0][wo]);
  gload16(pB1, &sB[0][2048 + wo]);
  __syncthreads();

  const int nt = K >> 5;
  int cur = 0;
  for (int tt = 0; tt < nt; ++tt) {
    if (tt + 1 < nt) {
      pA0 += 32; pA1 += 32; pB0 += 32; pB1 += 32;
      gload16(pA0, &sA[cur ^ 1][wo]);
      gload16(pA1, &sA[cur ^ 1][2048 + wo]);
      gload16(pB0, &sB[cur ^ 1][wo]);
      gload16(pB1, &sB[cur ^ 1][2048 + wo]);
    }
    bf16x8 wf[4], xf[4];
#pragma unroll
    for (int i = 0; i < 4; ++i) {
      int frow = wc * 64 + i * 16 + l15;
      int xrow = wr * 64 + i * 16 + l15;
      wf[i] = *(const bf16x8*)(&sB[cur][frow * 32 + ((kg ^ ((frow >> 1) & 3)) * 8)]);
      xf[i] = *(const bf16x8*)(&sA[cur][xrow * 32 + ((kg ^ ((xrow >> 1) & 3)) * 8)]);
    }
#pragma unroll
    for (int i = 0; i < 4; ++i)
#pragma unroll
      for (int j = 0; j < 4; ++j)
        acc[i][j] = __builtin_amdgcn_mfma_f32_16x16x32_bf16(wf[i], xf[j], acc[i][j], 0, 0, 0);
    __syncthreads();
    cur ^= 1;
  }

  float bvi[4][4];
#pragma unroll
  for (int i = 0; i < 4; ++i) {
    float4 b4 = *(const float4*)(bias + bn + wc * 64 + i * 16 + kg * 4);
    bvi[i][0] = b4.x; bvi[i][1] = b4.y; bvi[i][2] = b4.z; bvi[i][3] = b4.w;
  }
#pragma unroll
  for (int j = 0; j < 4; ++j) {
    const int token = bm + wr * 64 + j * 16 + l15;
    float ssum = 0.f;
#pragma unroll
    for (int i = 0; i < 4; ++i) {
      float v0 = acc[i][j][0] + bvi[i][0];
      float v1 = acc[i][j][1] + bvi[i][1];
      float v2 = acc[i][j][2] + bvi[i][2];
      float v3 = acc[i][j][3] + bvi[i][3];
      const size_t off = (size_t)token * N + bn + wc * 64 + i * 16 + kg * 4;
      if constexpr (std::is_same<TC, float>::value) {
        *(float4*)(C + off) = float4{v0, v1, v2, v3};
      } else {
        ushort4 pk{f2u(v0), f2u(v1), f2u(v2), f2u(v3)};
        *(ushort4*)(C + off) = pk;
      }
      if constexpr (SSNX > 0)
        ssum += v0 * v0 + v1 * v1 + v2 * v2 + v3 * v3;
    }
    if constexpr (SSNX > 0) {
      ssum += __shfl_xor(ssum, 16);
      ssum += __shfl_xor(ssum, 32);
      if (bx < SSNX && kg == 0)
        ssq[(size_t)token * (SSNX * 2) + bx * 2 + wc] = ssum;
    }
  }
}

// ---------------- finalize: partial sumsq -> per-token rsqrt scales -------
__global__ void finalize_rs_k(const float* __restrict__ pf,
                              const float* __restrict__ pc,
                              float* __restrict__ rsf, float* __restrict__ rsc) {
  int i = blockIdx.x * 256 + threadIdx.x;
  if (i >= TOKENS) return;
  float s = 0.f;
#pragma unroll
  for (int j = 0; j < 8; ++j) s += pf[(size_t)i * 8 + j];
  rsf[i] = rsqrtf(s * (1.f / 1024.f) + EPS_F);
  float c = 0.f;
#pragma unroll
  for (int j = 0; j < 4; ++j) c += pc[(size_t)i * 4 + j];
  rsc[i] = rsqrtf(c * (1.f / 256.f) + EPS_F);
}

// ---------------- MFMA windowed attention: one block per (window, head) ---
__global__ __launch_bounds__(256) void attn_mfma_k(
    const bf16* __restrict__ qkv, const bf16* __restrict__ cqk,
    const float* __restrict__ pos, const float* __restrict__ g_fqk,
    const float* __restrict__ g_cqk, const float* __restrict__ rs_f,
    const float* __restrict__ rs_c, bf16* __restrict__ aout) {
  __shared__ __align__(16) bf16 sQ[64][104], sK[64][104];
  __shared__ __align__(16) bf16 sVt[64][72];
  __shared__ __align__(16) bf16 sP[64][72];
  __shared__ float sPos[15][15];
  __shared__ float sRsF[64], sRsC[64];
  const int t = threadIdx.x, lane = t & 63, wave = t >> 6;
  const int head = blockIdx.x & 7;
  const int wid = blockIdx.x >> 3;
  const int wx = wid & 15, wy = (wid >> 4) & 15, b = wid >> 8;

  for (int i = t; i < 225; i += 256) sPos[i / 15][i % 15] = pos[i];
  if (t < 64) {
    const int y = ((wy << 3) + (t >> 3) + 4) & 127;
    const int x = ((wx << 3) + (t & 7) + 4) & 127;
    const size_t tok = ((size_t)b << 14) | (y << 7) | x;
    sRsF[t] = rs_f[tok];
    sRsC[t] = rs_c[tok];
  }
  {
    const int n = t >> 2, p = t & 3;
    const int y = ((wy << 3) + (n >> 3) + 4) & 127;
    const int x = ((wx << 3) + (n & 7) + 4) & 127;
    const size_t tok = ((size_t)b << 14) | (y << 7) | x;
    const bf16* row = qkv + tok * 1536;
    const int4* qp = (const int4*)(row + head * 64 + p * 16);
    ((int4*)&sQ[n][p * 16])[0] = qp[0];
    ((int4*)&sQ[n][p * 16])[1] = qp[1];
    {
      const bf16* kpp = row + 512 + head * 64 + p * 16;
      const float* gq = g_fqk + head * 64 + p * 16;
      const float* gk = g_fqk + 512 + head * 64 + p * 16;
      union { int4 v[2]; unsigned short s[16]; } kt;
#pragma unroll
      for (int i = 0; i < 16; ++i)
        kt.s[i] = f2u(b2f(kpp[i]) * gq[i] * gk[i]);
      ((int4*)&sK[n][p * 16])[0] = kt.v[0];
      ((int4*)&sK[n][p * 16])[1] = kt.v[1];
    }
    const bf16* vp = row + 1024 + head * 64 + p * 16;
#pragma unroll
    for (int i = 0; i < 16; ++i) sVt[p * 16 + i][n] = vp[i];
    const bf16* crow = cqk + tok * 256;
    if (p == 0) {
      const int4* cp = (const int4*)(crow + head * 16);
      ((int4*)&sQ[n][64])[0] = cp[0];
      ((int4*)&sQ[n][64])[1] = cp[1];
    } else if (p == 1) {
      const bf16* ckp = crow + 128 + head * 16;
      const float* gcq = g_cqk + head * 16;
      const float* gck = g_cqk + 128 + head * 16;
      union { int4 v[2]; unsigned short s[16]; } ct;
#pragma unroll
      for (int i = 0; i < 16; ++i)
        ct.s[i] = f2u(b2f(ckp[i]) * gcq[i] * gck[i]);
      ((int4*)&sK[n][64])[0] = ct.v[0];
      ((int4*)&sK[n][64])[1] = ct.v[1];
    } else if (p == 2) {
      ((int4*)&sQ[n][80])[0] = int4{0, 0, 0, 0};
      ((int4*)&sQ[n][80])[1] = int4{0, 0, 0, 0};
    } else {
      ((int4*)&sK[n][80])[0] = int4{0, 0, 0, 0};
      ((int4*)&sK[n][80])[1] = int4{0, 0, 0, 0};
    }
  }
  __syncthreads();

  const int l15 = lane & 15, kg = lane >> 4;
  bf16x8 qa[3];
#pragma unroll
  for (int ko = 0; ko < 3; ++ko)
    qa[ko] = *(const bf16x8*)&sQ[wave * 16 + l15][ko * 32 + kg * 8];
  f32x4 saccf[4] = {}, saccc[4] = {};
#pragma unroll
  for (int j = 0; j < 4; ++j) {
#pragma unroll
    for (int ko = 0; ko < 2; ++ko) {
      bf16x8 kb = *(const bf16x8*)&sK[j * 16 + l15][ko * 32 + kg * 8];
      saccf[j] = __builtin_amdgcn_mfma_f32_16x16x32_bf16(qa[ko], kb, saccf[j], 0, 0, 0);
    }
    bf16x8 kb2 = *(const bf16x8*)&sK[j * 16 + l15][64 + kg * 8];
    saccc[j] = __builtin_amdgcn_mfma_f32_16x16x32_bf16(qa[2], kb2, saccc[j], 0, 0, 0);
  }

  const bool lastx = (wx == 15), lasty = (wy == 15);
  float rqf[4], rqc[4];
#pragma unroll
  for (int r = 0; r < 4; ++r) {
    rqf[r] = sRsF[wave * 16 + kg * 4 + r];
    rqc[r] = sRsC[wave * 16 + kg * 4 + r];
  }
  float sv[4][4], mx[4], sum[4], inv[4];
#pragma unroll
  for (int r = 0; r < 4; ++r) mx[r] = -1e30f;
#pragma unroll
  for (int j = 0; j < 4; ++j) {
    int kcol = j * 16 + l15, kh = kcol >> 3, kw = kcol & 7;
    float rkf = sRsF[kcol], rkc = sRsC[kcol];
#pragma unroll
    for (int r = 0; r < 4; ++r) {
      int q = wave * 16 + kg * 4 + r, qh = q >> 3, qw = q & 7;
      bool msk = (lastx && ((qh >= 4) != (kh >= 4))) ||
                 (lasty && ((qw >= 4) != (kw >= 4)));
      float raw = saccf[j][r] * rqf[r] * rkf + saccc[j][r] * rqc[r] * rkc;
      float val = msk ? -1e30f : raw * SCALE_F + sPos[kh - qh + 7][kw - qw + 7];
      sv[j][r] = val;
      mx[r] = fmaxf(mx[r], val);
    }
  }
#pragma unroll
  for (int m = 1; m < 16; m <<= 1)
#pragma unroll
    for (int r = 0; r < 4; ++r) mx[r] = fmaxf(mx[r], __shfl_xor(mx[r], m));
#pragma unroll
  for (int r = 0; r < 4; ++r) sum[r] = 0.f;
#pragma unroll
  for (int j = 0; j < 4; ++j) {
    int kcol = j * 16 + l15;
#pragma unroll
    for (int r = 0; r < 4; ++r) {
      float e = __expf(sv[j][r] - mx[r]);
      sum[r] += e;
      sP[wave * 16 + kg * 4 + r][kcol] = __float2bfloat16(e);
    }
  }
#pragma unroll
  for (int m = 1; m < 16; m <<= 1)
#pragma unroll
    for (int r = 0; r < 4; ++r) sum[r] += __shfl_xor(sum[r], m);
#pragma unroll
  for (int r = 0; r < 4; ++r) inv[r] = 1.f / sum[r];
  __syncthreads();

  bf16x8 pa[2];
#pragma unroll
  for (int ko = 0; ko < 2; ++ko)
    pa[ko] = *(const bf16x8*)&sP[wave * 16 + l15][ko * 32 + kg * 8];
  f32x4 oacc[4] = {};
#pragma unroll
  for (int jf = 0; jf < 4; ++jf)
#pragma unroll
    for (int ko = 0; ko < 2; ++ko) {
      bf16x8 vb = *(const bf16x8*)&sVt[jf * 16 + l15][ko * 32 + kg * 8];
      oacc[jf] = __builtin_amdgcn_mfma_f32_16x16x32_bf16(pa[ko], vb, oacc[jf], 0, 0, 0);
    }
#pragma unroll
  for (int r = 0; r < 4; ++r) {
    int q = wave * 16 + kg * 4 + r;
    const int y = ((wy << 3) + (q >> 3) + 4) & 127;
    const int x = ((wx << 3) + (q & 7) + 4) & 127;
    const size_t tok = ((size_t)b << 14) | (y << 7) | x;
    bf16* dst = aout + tok * 512 + head * 64;
#pragma unroll
    for (int jf = 0; jf < 4; ++jf)
      dst[jf * 16 + l15] = __float2bfloat16(oacc[jf][r] * inv[r]);
  }
}

extern "C" void kernel_launch(void* const* d_in, const int* in_sizes, int n_in,
                              void* d_out, int out_size, void* d_ws, size_t ws_size,
                              hipStream_t stream) {
  const float* features = (const float*)d_in[0];
  const float* coords   = (const float*)d_in[1];
  const float* w_fqk = (const float*)d_in[2];
  const float* b_fqk = (const float*)d_in[3];
  const float* g_fqk = (const float*)d_in[4];
  const float* w_cqk = (const float*)d_in[5];
  const float* b_cqk = (const float*)d_in[6];
  const float* g_cqk = (const float*)d_in[7];
  const float* w_v   = (const float*)d_in[8];
  const float* b_v   = (const float*)d_in[9];
  const float* w_out = (const float*)d_in[10];
  const float* b_out = (const float*)d_in[11];
  const float* pos_emb = (const float*)d_in[12];
  float* out = (float*)d_out;

  const int M = TOKENS;  // 65536
  bf16* qkv   = (bf16*)d_ws;                       // M*1536 (raw q|k|v)
  bf16* cqk   = qkv + (size_t)M * 1536;            // M*256 (raw cq|ck)
  bf16* aout  = cqk + (size_t)M * 256;             // M*512
  bf16* wcombT = aout + (size_t)M * 512;           // 1536*512
  bf16* wcqkT  = wcombT + (size_t)1536 * 512;      // 256*128
  bf16* woutT  = wcqkT + 256 * 128;                // 512*512
  float* bias_comb = (float*)(woutT + 512 * 512);  // 1536 f32
  float* ssq_f = bias_comb + 1536;                 // M*8 f32
  float* ssq_c = ssq_f + (size_t)M * 8;            // M*4 f32
  float* rs_f  = ssq_c + (size_t)M * 4;            // M f32
  float* rs_c  = rs_f + M;                         // M f32
  bf16* fb16 = (bf16*)d_out;                       // M*512 (aliased, dead)
  bf16* cb16 = fb16 + (size_t)M * 512;             // M*128

  convert_k<<<2048, 256, 0, stream>>>(features, fb16, (long)M * 512);
  convert_k<<<1024, 256, 0, stream>>>(coords, cb16, (long)M * 128);
  transpose_k<<<(512 * 1024 + 255) / 256, 256, 0, stream>>>(w_fqk, wcombT, 512, 1024);
  transpose_k<<<(512 * 512 + 255) / 256, 256, 0, stream>>>(w_v, wcombT + (size_t)1024 * 512, 512, 512);
  transpose_k<<<(128 * 256 + 255) / 256, 256, 0, stream>>>(w_cqk, wcqkT, 128, 256);
  transpose_k<<<(512 * 512 + 255) / 256, 256, 0, stream>>>(w_out, woutT, 512, 512);
  biascat_k<<<6, 256, 0, stream>>>(b_fqk, b_v, bias_comb);

  // fused qk+v projection (256^2 4-phase pipeline; + q|k sumsq partials)
  gemm256p_k<bf16, 4><<<dim3(6, 256), 512, 131072, stream>>>(fb16, wcombT, bias_comb, qkv, ssq_f, M, 1536, 512);
  // coord projection (small: keep 128^2 kernel)
  gemm128_k<bf16, 2><<<dim3(2, 512), 256, 0, stream>>>(cb16, wcqkT, b_cqk, cqk, ssq_c, M, 256, 128);
  finalize_rs_k<<<TOKENS / 256, 256, 0, stream>>>(ssq_f, ssq_c, rs_f, rs_c);
  attn_mfma_k<<<4 * 16 * 16 * 8, 256, 0, stream>>>(qkv, cqk, pos_emb, g_fqk, g_cqk, rs_f, rs_c, aout);
  // output projection (256^2 pipeline, f32 out)
  gemm256p_k<float, 0><<<dim3(2, 256), 512, 131072, stream>>>(aout, woutT, b_out, out, nullptr, M, 512, 512);
}